// Round 2
// baseline (242.214 us; speedup 1.0000x reference)
//
#include <hip/hip_runtime.h>

#define CH 256
#define HH 128
#define WW 128
#define HW (HH * WW)
#define SEGH 16   // rows per vertical segment
#define NSEG 8    // 128 / SEGH

__device__ __forceinline__ float rdlane(float v, int l) {
    return __int_as_float(__builtin_amdgcn_readlane(__float_as_int(v), l));
}
__device__ __forceinline__ float uni(float v) {
    return __int_as_float(__builtin_amdgcn_readfirstlane(__float_as_int(v)));
}

// One block per (b,c) image. 1024 threads (16 waves).
// Dynamic LDS: 64 KiB result plane + 8 KiB segment scratch = 72 KiB (2 blocks/CU).
//
//   Params:  lane-split transcendentals (lanes 0-11), broadcast via v_readlane.
//   Phase H: thread = (row, chunk): 8 threads per row, 16 CONTIGUOUS elements
//            each (64 B float4 loads). Local Horner compose + 3-step KS over
//            8 lanes (8 shuffles/thread vs 48 in the old 32-lane scheme).
//            Writes m0*lr + m1*rl to the plane with an XOR-swizzled float4
//            slot (col ^= (row&3)<<2) -> conflict-free b128 writes.
//   Phase V1: thread=(col,seg); loads 16-row column chunk into registers
//            xv[16] (live across the barrier), computes segment exit states
//            b2/b3, writes 8 KiB scratch.
//   --- one __syncthreads ---
//   Fixup:   compose incoming states Sin/Tin from <=7 summaries (wave-uniform
//            trip counts).
//   Phase V2: forward tb chain + single swizzled LDS read/element into o[16]
//            regs; backward bt chain + coalesced store. 16 DS reads total.
__global__ __launch_bounds__(1024, 2) void dscan_kernel(
    const float* __restrict__ x,
    const float* __restrict__ decay_logits,
    const float* __restrict__ mix_logits,
    const float* __restrict__ input_scale,
    float* __restrict__ out)
{
    extern __shared__ float smem[];
    float* __restrict__ xs  = smem;           // 16384 floats: result plane (swizzled)
    float* __restrict__ scr = smem + HW;      // 2048 floats: b2 (1024) + b3 (1024)

    const int img  = blockIdx.x;              // b*256 + c
    const int c    = img & (CH - 1);
    const int tid  = threadIdx.x;
    const int lane = tid & 63;

    // ---- lane-split per-channel params ----
    // lanes 0-3: clamped sigmoid(decay); 4-7: softmax numerators; 8-11: 1+tanh
    float pv = 0.0f;
    {
        const int j = lane & 3;
        const int g = lane >> 2;
        if (g == 0) {
            const float v = decay_logits[j * CH + c];
            pv = fminf(fmaxf(1.0f / (1.0f + expf(-v)), 0.05f), 0.995f);
        } else if (g == 1) {
            const float a0 = mix_logits[0 * CH + c];
            const float a1 = mix_logits[1 * CH + c];
            const float a2 = mix_logits[2 * CH + c];
            const float a3 = mix_logits[3 * CH + c];
            const float mm = fmaxf(fmaxf(a0, a1), fmaxf(a2, a3));
            const float aj = (j == 0) ? a0 : (j == 1) ? a1 : (j == 2) ? a2 : a3;
            pv = expf(aj - mm);
        } else if (g == 2) {
            pv = 1.0f + tanhf(input_scale[j * CH + c]);
        }
    }
    const float d0 = rdlane(pv, 0), d1 = rdlane(pv, 1);
    const float d2 = rdlane(pv, 2), d3 = rdlane(pv, 3);
    const float e0 = rdlane(pv, 4), e1 = rdlane(pv, 5);
    const float e2 = rdlane(pv, 6), e3 = rdlane(pv, 7);
    const float s0 = rdlane(pv, 8), s1 = rdlane(pv, 9);
    const float s2 = rdlane(pv, 10), s3 = rdlane(pv, 11);

    const float einv = uni(1.0f / (e0 + e1 + e2 + e3));
    const float m0 = uni(e0 * einv), m1 = uni(e1 * einv);
    const float m2 = uni(e2 * einv), m3 = uni(e3 * einv);
    const float c0 = uni((1.0f - d0) * s0);   // s = d*s + c*x
    const float c1 = uni((1.0f - d1) * s1);
    const float c2 = uni((1.0f - d2) * s2);
    const float c3 = uni((1.0f - d3) * s3);

    // KS powers: q[k] = d^(16*2^k), k=0..2 (chunk width 16, 8 chunks/row)
    float q0[3], q1[3];
    {
        float a = d0 * d0; a = a * a; a = a * a; a = a * a;   // d0^16
        q0[0] = uni(a); q0[1] = uni(q0[0] * q0[0]); q0[2] = uni(q0[1] * q0[1]);
        float b = d1 * d1; b = b * b; b = b * b; b = b * b;   // d1^16
        q1[0] = uni(b); q1[1] = uni(q1[0] * q1[0]); q1[2] = uni(q1[1] * q1[1]);
    }
    float t2v = d2 * d2; t2v = t2v * t2v; t2v = t2v * t2v; const float d2p16 = uni(t2v * t2v);
    float t3v = d3 * d3; t3v = t3v * t3v; t3v = t3v * t3v; const float d3p16 = uni(t3v * t3v);

    const float* __restrict__ xg = x + (size_t)img * HW;
    float* __restrict__ og = out + (size_t)img * HW;

    // ---- Phase H: 8 threads/row, 16 contiguous elems each, 3-step KS ----
    {
        const int hr = tid >> 3;          // row 0..127
        const int hk = tid & 7;           // chunk 0..7

        const float* __restrict__ xrow = xg + hr * WW + hk * 16;
        const float4 a0 = *(const float4*)(xrow + 0);
        const float4 a1 = *(const float4*)(xrow + 4);
        const float4 a2 = *(const float4*)(xrow + 8);
        const float4 a3 = *(const float4*)(xrow + 12);
        float xr[16];
        xr[0]=a0.x;  xr[1]=a0.y;  xr[2]=a0.z;  xr[3]=a0.w;
        xr[4]=a1.x;  xr[5]=a1.y;  xr[6]=a1.z;  xr[7]=a1.w;
        xr[8]=a2.x;  xr[9]=a2.y;  xr[10]=a2.z; xr[11]=a2.w;
        xr[12]=a3.x; xr[13]=a3.y; xr[14]=a3.z; xr[15]=a3.w;

        // local inclusive compose over the 16 elements, both directions
        float bL = c0 * xr[0];
#pragma unroll
        for (int i = 1; i < 16; ++i) bL = fmaf(d0, bL, c0 * xr[i]);
        float bR = c1 * xr[15];
#pragma unroll
        for (int i = 14; i >= 0; --i) bR = fmaf(d1, bR, c1 * xr[i]);

        // constant-decay Kogge-Stone over the 8 chunks of this row
#pragma unroll
        for (int kk = 0; kk < 3; ++kk) {
            const int off = 1 << kk;
            const float bU = __shfl_up(bL, (unsigned)off, 8);
            bL = fmaf(q0[kk], (hk >= off) ? bU : 0.0f, bL);
            const float bD = __shfl_down(bR, (unsigned)off, 8);
            bR = fmaf(q1[kk], (hk < 8 - off) ? bD : 0.0f, bR);
        }
        // exclusive incoming states
        float EL = __shfl_up(bL, 1u, 8);
        if (hk == 0) EL = 0.0f;
        float ER = __shfl_down(bR, 1u, 8);
        if (hk == 7) ER = 0.0f;

        // recompute elementwise (exact serial recurrence from composed states)
        float rr[16];
        float t = ER;
#pragma unroll
        for (int i = 15; i >= 0; --i) { t = fmaf(d1, t, c1 * xr[i]); rr[i] = t; }

        float l = EL;
        float* __restrict__ prow = xs + hr * WW + hk * 16;
        const int rsw = hr & 3;           // float4-slot swizzle key
#pragma unroll
        for (int j = 0; j < 4; ++j) {
            float4 o4;
            l = fmaf(d0, l, c0 * xr[4*j + 0]); o4.x = fmaf(m0, l, m1 * rr[4*j + 0]);
            l = fmaf(d0, l, c0 * xr[4*j + 1]); o4.y = fmaf(m0, l, m1 * rr[4*j + 1]);
            l = fmaf(d0, l, c0 * xr[4*j + 2]); o4.z = fmaf(m0, l, m1 * rr[4*j + 2]);
            l = fmaf(d0, l, c0 * xr[4*j + 3]); o4.w = fmaf(m0, l, m1 * rr[4*j + 3]);
            *(float4*)(prow + 4 * (j ^ rsw)) = o4;   // swizzled slot: conflict-free
        }
    }

    // ---- Phase V1: load column chunk to registers, segment summaries ----
    const int col = tid & (WW - 1);       // 0..127
    const int seg = tid >> 7;             // 0..7
    const float* __restrict__ xcol = xg + seg * SEGH * WW + col;

    float xv[SEGH];                       // lives across the barrier (16 VGPRs)
#pragma unroll
    for (int i = 0; i < SEGH; ++i) xv[i] = xcol[i * WW];   // L2-warm

    {
        float b2 = 0.0f;
#pragma unroll
        for (int i = 0; i < SEGH; ++i) b2 = fmaf(d2, b2, c2 * xv[i]);

        float b3 = 0.0f;                  // backward Horner: sum d3^i * xv[i]
#pragma unroll
        for (int i = SEGH - 1; i >= 0; --i) b3 = fmaf(d3, b3, xv[i]);
        b3 *= c3;

        scr[tid]        = b2;
        scr[1024 + tid] = b3;
    }

    __syncthreads();   // the ONE barrier

    // ---- Fixup: incoming states per (col, seg); trip counts wave-uniform ----
    float Sin = 0.0f;
    for (int j = 0; j < seg; ++j)
        Sin = fmaf(d2p16, Sin, scr[j * WW + col]);
    float Tin = 0.0f;
    for (int j = NSEG - 1; j > seg; --j)
        Tin = fmaf(d3p16, Tin, scr[1024 + j * WW + col]);

    // ---- Phase V2: forward tb + swizzled plane read into regs; backward bt ----
    {
        const int rbase = seg * SEGH;
        float o[SEGH];
        float s = Sin;
#pragma unroll
        for (int i = 0; i < SEGH; ++i) {
            s = fmaf(d2, s, c2 * xv[i]);
            // plane row R = rbase+i has R&3 == i&3 (rbase multiple of 16)
            const float h = xs[(rbase + i) * WW + (col ^ ((i & 3) << 2))];
            o[i] = fmaf(m2, s, h);
        }
        float t = Tin;
        float* __restrict__ ocol = og + rbase * WW + col;
#pragma unroll
        for (int i = SEGH - 1; i >= 0; --i) {
            t = fmaf(d3, t, c3 * xv[i]);
            ocol[i * WW] = fmaf(m3, t, o[i]);
        }
    }
}

extern "C" void kernel_launch(void* const* d_in, const int* in_sizes, int n_in,
                              void* d_out, int out_size, void* d_ws, size_t ws_size,
                              hipStream_t stream) {
    const float* x  = (const float*)d_in[0];
    const float* dl = (const float*)d_in[1];
    const float* ml = (const float*)d_in[2];
    const float* is = (const float*)d_in[3];
    float* out = (float*)d_out;

    const size_t lds_bytes = (size_t)(HW + 2048) * sizeof(float);   // 73728

    static bool attr_set = false;   // idempotent host-side attribute; value never changes
    if (!attr_set) {
        (void)hipFuncSetAttribute((const void*)dscan_kernel,
                                  hipFuncAttributeMaxDynamicSharedMemorySize,
                                  (int)lds_bytes);
        attr_set = true;
    }

    dim3 grid(2048), block(1024);
    hipLaunchKernelGGL(dscan_kernel, grid, block, lds_bytes, stream, x, dl, ml, is, out);
}

// Round 3
// 240.925 us; speedup vs baseline: 1.0053x; 1.0053x over previous
//
#include <hip/hip_runtime.h>

#define CH 256
#define HH 128
#define WW 128
#define HW (HH * WW)
#define SEGH 16   // rows per vertical segment
#define NSEG 8    // 128 / SEGH

__device__ __forceinline__ float rdlane(float v, int l) {
    return __int_as_float(__builtin_amdgcn_readlane(__float_as_int(v), l));
}
__device__ __forceinline__ float uni(float v) {
    return __int_as_float(__builtin_amdgcn_readfirstlane(__float_as_int(v)));
}

// One block per (b,c) image. 1024 threads (16 waves). LDS 72 KiB, 2 blocks/CU
// (32 waves = HW max for this CU).
//
//   Params:  lane-split transcendentals (lanes 0-11), broadcast via v_readlane.
//   Phase H: thread = (row, chunk): 8 threads/row, 16 contiguous elems each.
//            Local compose split into 2 independent 8-deep Horner halves
//            (joined with d^8), 3-step KS over 8 lanes, exact recompute.
//            Plane store swizzle: logical float4 (hk,j) -> physical slot
//            P = (hk ^ 2j) + 8j.  Write: fixed j, hk=0..7 -> P%8 bijective ->
//            conflict-free b128. Read: 64 consecutive cols -> each bank
//            exactly 2 lanes -> free. (Round-2's j^rsw swizzle was 4-way
//            conflicted in 8-lane batches: 3.1M conflict cycles, matched.)
//   Phase V1: loads issued EARLY (right after H's local compose) so the tail
//            of H compute hides their L2 latency. xv[16] lives across the
//            barrier; segment exit states b2/b3 -> 8 KiB scratch.
//   --- one __syncthreads ---
//   Fixup:   incoming states from <=7 summaries (wave-uniform trip counts).
//   Phase V2: forward tb + swizzled plane read (row-independent offset),
//            backward bt + coalesced store.
__global__ __launch_bounds__(1024, 8) void dscan_kernel(
    const float* __restrict__ x,
    const float* __restrict__ decay_logits,
    const float* __restrict__ mix_logits,
    const float* __restrict__ input_scale,
    float* __restrict__ out)
{
    extern __shared__ float smem[];
    float* __restrict__ xs  = smem;           // 16384 floats: result plane (swizzled)
    float* __restrict__ scr = smem + HW;      // 2048 floats: b2 (1024) + b3 (1024)

    const int img  = blockIdx.x;              // b*256 + c
    const int c    = img & (CH - 1);
    const int tid  = threadIdx.x;
    const int lane = tid & 63;

    // ---- lane-split per-channel params ----
    float pv = 0.0f;
    {
        const int j = lane & 3;
        const int g = lane >> 2;
        if (g == 0) {
            const float v = decay_logits[j * CH + c];
            pv = fminf(fmaxf(1.0f / (1.0f + expf(-v)), 0.05f), 0.995f);
        } else if (g == 1) {
            const float a0 = mix_logits[0 * CH + c];
            const float a1 = mix_logits[1 * CH + c];
            const float a2 = mix_logits[2 * CH + c];
            const float a3 = mix_logits[3 * CH + c];
            const float mm = fmaxf(fmaxf(a0, a1), fmaxf(a2, a3));
            const float aj = (j == 0) ? a0 : (j == 1) ? a1 : (j == 2) ? a2 : a3;
            pv = expf(aj - mm);
        } else if (g == 2) {
            pv = 1.0f + tanhf(input_scale[j * CH + c]);
        }
    }
    const float d0 = rdlane(pv, 0), d1 = rdlane(pv, 1);
    const float d2 = rdlane(pv, 2), d3 = rdlane(pv, 3);
    const float e0 = rdlane(pv, 4), e1 = rdlane(pv, 5);
    const float e2 = rdlane(pv, 6), e3 = rdlane(pv, 7);
    const float s0 = rdlane(pv, 8), s1 = rdlane(pv, 9);
    const float s2 = rdlane(pv, 10), s3 = rdlane(pv, 11);

    const float einv = uni(1.0f / (e0 + e1 + e2 + e3));
    const float m0 = uni(e0 * einv), m1 = uni(e1 * einv);
    const float m2 = uni(e2 * einv), m3 = uni(e3 * einv);
    const float c0 = uni((1.0f - d0) * s0);   // s = d*s + c*x
    const float c1 = uni((1.0f - d1) * s1);
    const float c2 = uni((1.0f - d2) * s2);
    const float c3 = uni((1.0f - d3) * s3);

    // powers: p8 = d^8 (compose join), q[k] = d^(16*2^k) (KS steps)
    float p8_0, p8_1, q0[3], q1[3];
    {
        float a = d0 * d0; a = a * a;             // d0^4
        p8_0 = uni(a * a);                        // d0^8
        q0[0] = uni(p8_0 * p8_0); q0[1] = uni(q0[0] * q0[0]); q0[2] = uni(q0[1] * q0[1]);
        float b = d1 * d1; b = b * b;
        p8_1 = uni(b * b);
        q1[0] = uni(p8_1 * p8_1); q1[1] = uni(q1[0] * q1[0]); q1[2] = uni(q1[1] * q1[1]);
    }
    float t2v = d2 * d2; t2v = t2v * t2v; t2v = t2v * t2v; const float d2p16 = uni(t2v * t2v);
    float t3v = d3 * d3; t3v = t3v * t3v; t3v = t3v * t3v; const float d3p16 = uni(t3v * t3v);

    const float* __restrict__ xg = x + (size_t)img * HW;
    float* __restrict__ og = out + (size_t)img * HW;

    const int col = tid & (WW - 1);       // V-phase column 0..127
    const int seg = tid >> 7;             // V-phase segment 0..7
    const float* __restrict__ xcol = xg + seg * SEGH * WW + col;
    float xv[SEGH];                       // V1 data, lives across the barrier

    // ---- Phase H ----
    {
        const int hr = tid >> 3;          // row 0..127
        const int hk = tid & 7;           // chunk 0..7

        const float* __restrict__ xrow = xg + hr * WW + hk * 16;
        const float4 a0 = *(const float4*)(xrow + 0);
        const float4 a1 = *(const float4*)(xrow + 4);
        const float4 a2 = *(const float4*)(xrow + 8);
        const float4 a3 = *(const float4*)(xrow + 12);
        float xr[16];
        xr[0]=a0.x;  xr[1]=a0.y;  xr[2]=a0.z;  xr[3]=a0.w;
        xr[4]=a1.x;  xr[5]=a1.y;  xr[6]=a1.z;  xr[7]=a1.w;
        xr[8]=a2.x;  xr[9]=a2.y;  xr[10]=a2.z; xr[11]=a2.w;
        xr[12]=a3.x; xr[13]=a3.y; xr[14]=a3.z; xr[15]=a3.w;

        // local compose, two independent 8-deep halves per direction
        float blo = c0 * xr[0];
#pragma unroll
        for (int i = 1; i < 8; ++i)  blo = fmaf(d0, blo, c0 * xr[i]);
        float bhi = c0 * xr[8];
#pragma unroll
        for (int i = 9; i < 16; ++i) bhi = fmaf(d0, bhi, c0 * xr[i]);
        float bL = fmaf(p8_0, blo, bhi);

        float rA = c1 * xr[15];
#pragma unroll
        for (int i = 14; i >= 8; --i) rA = fmaf(d1, rA, c1 * xr[i]);
        float rB = c1 * xr[7];
#pragma unroll
        for (int i = 6; i >= 0; --i)  rB = fmaf(d1, rB, c1 * xr[i]);
        float bR = fmaf(p8_1, rA, rB);

        // EARLY-ISSUE Phase V1 loads: H's loads have returned (consumed by the
        // composes above); the KS + recompute + stores below hide L2 latency.
#pragma unroll
        for (int i = 0; i < SEGH; ++i) xv[i] = xcol[i * WW];

        // constant-decay Kogge-Stone over the 8 chunks of this row
#pragma unroll
        for (int kk = 0; kk < 3; ++kk) {
            const int off = 1 << kk;
            const float bU = __shfl_up(bL, (unsigned)off, 8);
            bL = fmaf(q0[kk], (hk >= off) ? bU : 0.0f, bL);
            const float bD = __shfl_down(bR, (unsigned)off, 8);
            bR = fmaf(q1[kk], (hk < 8 - off) ? bD : 0.0f, bR);
        }
        // exclusive incoming states
        float EL = __shfl_up(bL, 1u, 8);
        if (hk == 0) EL = 0.0f;
        float ER = __shfl_down(bR, 1u, 8);
        if (hk == 7) ER = 0.0f;

        // exact elementwise recompute
        float rr[16];
        float t = ER;
#pragma unroll
        for (int i = 15; i >= 0; --i) { t = fmaf(d1, t, c1 * xr[i]); rr[i] = t; }

        float l = EL;
        float* __restrict__ prow = xs + hr * WW;
#pragma unroll
        for (int j = 0; j < 4; ++j) {
            float4 o4;
            l = fmaf(d0, l, c0 * xr[4*j + 0]); o4.x = fmaf(m0, l, m1 * rr[4*j + 0]);
            l = fmaf(d0, l, c0 * xr[4*j + 1]); o4.y = fmaf(m0, l, m1 * rr[4*j + 1]);
            l = fmaf(d0, l, c0 * xr[4*j + 2]); o4.z = fmaf(m0, l, m1 * rr[4*j + 2]);
            l = fmaf(d0, l, c0 * xr[4*j + 3]); o4.w = fmaf(m0, l, m1 * rr[4*j + 3]);
            // physical slot P = (hk ^ 2j) + 8j : bijective, conflict-free both sides
            *(float4*)(prow + 4 * ((hk ^ (2*j)) + 8*j)) = o4;
        }
    }

    // ---- Phase V1: segment summaries from xv (already loaded) ----
    {
        float b2 = 0.0f;
#pragma unroll
        for (int i = 0; i < SEGH; ++i) b2 = fmaf(d2, b2, c2 * xv[i]);

        float b3 = 0.0f;                  // backward Horner: sum d3^i * xv[i]
#pragma unroll
        for (int i = SEGH - 1; i >= 0; --i) b3 = fmaf(d3, b3, xv[i]);
        b3 *= c3;

        scr[tid]        = b2;
        scr[1024 + tid] = b3;
    }

    __syncthreads();   // the ONE barrier

    // ---- Fixup: incoming states per (col, seg); wave-uniform trip counts ----
    float Sin = 0.0f;
    for (int j = 0; j < seg; ++j)
        Sin = fmaf(d2p16, Sin, scr[j * WW + col]);
    float Tin = 0.0f;
    for (int j = NSEG - 1; j > seg; --j)
        Tin = fmaf(d3p16, Tin, scr[1024 + j * WW + col]);

    // ---- Phase V2: forward tb + swizzled plane read; backward bt + store ----
    {
        const int rbase = seg * SEGH;
        // row-independent swizzled offset for this column
        const int hkc = col >> 4;
        const int jc  = (col >> 2) & 3;
        const int off = 4 * ((hkc ^ (2*jc)) + 8*jc) + (col & 3);
        const float* __restrict__ pcol = xs + rbase * WW + off;

        float o[SEGH];
        float s = Sin;
#pragma unroll
        for (int i = 0; i < SEGH; ++i) {
            s = fmaf(d2, s, c2 * xv[i]);
            o[i] = fmaf(m2, s, pcol[i * WW]);
        }
        float t = Tin;
        float* __restrict__ ocol = og + rbase * WW + col;
#pragma unroll
        for (int i = SEGH - 1; i >= 0; --i) {
            t = fmaf(d3, t, c3 * xv[i]);
            ocol[i * WW] = fmaf(m3, t, o[i]);
        }
    }
}

extern "C" void kernel_launch(void* const* d_in, const int* in_sizes, int n_in,
                              void* d_out, int out_size, void* d_ws, size_t ws_size,
                              hipStream_t stream) {
    const float* x  = (const float*)d_in[0];
    const float* dl = (const float*)d_in[1];
    const float* ml = (const float*)d_in[2];
    const float* is = (const float*)d_in[3];
    float* out = (float*)d_out;

    const size_t lds_bytes = (size_t)(HW + 2048) * sizeof(float);   // 73728

    static bool attr_set = false;   // idempotent host-side attribute; value never changes
    if (!attr_set) {
        (void)hipFuncSetAttribute((const void*)dscan_kernel,
                                  hipFuncAttributeMaxDynamicSharedMemorySize,
                                  (int)lds_bytes);
        attr_set = true;
    }

    dim3 grid(2048), block(1024);
    hipLaunchKernelGGL(dscan_kernel, grid, block, lds_bytes, stream, x, dl, ml, is, out);
}